// Round 1
// baseline (211.936 us; speedup 1.0000x reference)
//
#include <hip/hip_runtime.h>
#include <cstdint>

#define NROWS 8192   // 2N
#define NHALF 4096   // N
#define DDIM  512
#define INV_TAU 10.0f
#define BM 128
#define BN 128
#define BK 64
#define NKT (DDIM / BK)   // 8
#define NBJ (NROWS / BN)  // 64

typedef __bf16 bf16x8 __attribute__((ext_vector_type(8)));
typedef float  f32x4  __attribute__((ext_vector_type(4)));

__device__ __forceinline__ unsigned short f2bf(float f) {
  unsigned int u = __float_as_uint(f);
  u += 0x7fffu + ((u >> 16) & 1u);   // round-to-nearest-even
  return (unsigned short)(u >> 16);
}
__device__ __forceinline__ float bf2f(unsigned short h) {
  return __uint_as_float(((unsigned int)h) << 16);
}

__device__ __forceinline__ void gload16(const void* g, void* l) {
  __builtin_amdgcn_global_load_lds(
      (__attribute__((address_space(1))) void*)g,
      (__attribute__((address_space(3))) void*)l, 16, 0, 0);
}

// ---------------- Kernel A: row-normalize to bf16, zero out ----------------
__global__ void __launch_bounds__(256) norm_kernel(
    const float* __restrict__ x1, const float* __restrict__ x2,
    unsigned short* __restrict__ zn, float* __restrict__ out)
{
  const int w = threadIdx.x >> 6;
  const int lane = threadIdx.x & 63;
  const int row = blockIdx.x * 4 + w;
  const float* src = (row < NHALF) ? (x1 + (size_t)row * DDIM)
                                   : (x2 + (size_t)(row - NHALF) * DDIM);
  const float4* s4 = (const float4*)src;
  float4 v0 = s4[lane];
  float4 v1 = s4[lane + 64];
  float ss = v0.x*v0.x + v0.y*v0.y + v0.z*v0.z + v0.w*v0.w
           + v1.x*v1.x + v1.y*v1.y + v1.z*v1.z + v1.w*v1.w;
  #pragma unroll
  for (int off = 32; off >= 1; off >>= 1) ss += __shfl_xor(ss, off);
  const float inv = 1.0f / fmaxf(sqrtf(ss), 1e-8f);
  ushort4 o0, o1;
  o0.x = f2bf(v0.x * inv); o0.y = f2bf(v0.y * inv);
  o0.z = f2bf(v0.z * inv); o0.w = f2bf(v0.w * inv);
  o1.x = f2bf(v1.x * inv); o1.y = f2bf(v1.y * inv);
  o1.z = f2bf(v1.z * inv); o1.w = f2bf(v1.w * inv);
  ushort4* d4 = (ushort4*)(zn + (size_t)row * DDIM);
  d4[lane] = o0;
  d4[lane + 64] = o1;
  if (row == 0 && lane == 0) out[0] = 0.0f;
}

// ------ Kernel B: fused Gram GEMM + exp + mask + row-sum (per col-panel) ----
__global__ void __launch_bounds__(256) simexp_kernel(
    const unsigned short* __restrict__ zn, float* __restrict__ partial)
{
  __shared__ unsigned short As[BM * BK];
  __shared__ unsigned short Bs[BN * BK];
  __shared__ float rowsum[2][BM];

  const int t = threadIdx.x;
  const int lane = t & 63;
  const int w = t >> 6;
  const int waveRow = w & 1;   // 2x2 waves -> 64x64 quadrant each
  const int waveCol = w >> 1;
  const int rowBase = blockIdx.x * BM;
  const int colBase = blockIdx.y * BN;
  const int quad = lane >> 4;
  const int cl = lane & 15;

  f32x4 acc[4][4];
  #pragma unroll
  for (int i = 0; i < 4; ++i)
    #pragma unroll
    for (int j = 0; j < 4; ++j)
      acc[i][j] = (f32x4)0.0f;

  for (int kt = 0; kt < NKT; ++kt) {
    const int kbase = kt * BK;
    // stage A (128xBK) and B (128xBK) tiles: 1024 chunks of 16B each, 4/thread
    #pragma unroll
    for (int qq = 0; qq < 4; ++qq) {
      const int chunk = qq * 256 + t;
      const int rr = chunk >> 3;       // tile row
      const int k8 = chunk & 7;        // 16B chunk within row
      gload16(zn + (size_t)(rowBase + rr) * DDIM + kbase + k8 * 8, &As[chunk * 8]);
      gload16(zn + (size_t)(colBase + rr) * DDIM + kbase + k8 * 8, &Bs[chunk * 8]);
    }
    __syncthreads();   // compiler drains vmcnt before barrier
    #pragma unroll
    for (int ks = 0; ks < 2; ++ks) {
      const int ko = ks * 32 + quad * 8;
      bf16x8 a[4], b[4];
      #pragma unroll
      for (int ti = 0; ti < 4; ++ti)
        a[ti] = *(const bf16x8*)&As[(waveRow * 64 + ti * 16 + cl) * BK + ko];
      #pragma unroll
      for (int tj = 0; tj < 4; ++tj)
        b[tj] = *(const bf16x8*)&Bs[(waveCol * 64 + tj * 16 + cl) * BK + ko];
      #pragma unroll
      for (int ti = 0; ti < 4; ++ti)
        #pragma unroll
        for (int tj = 0; tj < 4; ++tj)
          acc[ti][tj] = __builtin_amdgcn_mfma_f32_16x16x32_bf16(
              a[ti], b[tj], acc[ti][tj], 0, 0, 0);
    }
    __syncthreads();
  }

  // epilogue: sim = acc*10; mask (r%N == c%N); exp; row-sum over this 128-col panel
  #pragma unroll
  for (int ti = 0; ti < 4; ++ti) {
    #pragma unroll
    for (int r = 0; r < 4; ++r) {
      const int lrow = waveRow * 64 + ti * 16 + quad * 4 + r;  // C/D: row=(lane>>4)*4+reg
      const int grow = rowBase + lrow;
      float s = 0.0f;
      #pragma unroll
      for (int tj = 0; tj < 4; ++tj) {
        const int gcol = colBase + waveCol * 64 + tj * 16 + cl; // C/D: col=lane&15
        const float sim = acc[ti][tj][r] * INV_TAU;
        s += (((grow ^ gcol) & (NHALF - 1)) == 0) ? 0.0f : __expf(sim);
      }
      // reduce across the 16 lanes holding this row's columns
      s += __shfl_xor(s, 1); s += __shfl_xor(s, 2);
      s += __shfl_xor(s, 4); s += __shfl_xor(s, 8);
      if (cl == 0) rowsum[waveCol][lrow] = s;
    }
  }
  __syncthreads();
  if (t < BM)
    partial[(size_t)blockIdx.y * NROWS + rowBase + t] = rowsum[0][t] + rowsum[1][t];
}

// -------- Kernel C1: denom = sum over col-panels; += log(denom)/2N ---------
__global__ void __launch_bounds__(256) logdenom_kernel(
    const float* __restrict__ partial, float* __restrict__ out)
{
  const int r = blockIdx.x * 256 + threadIdx.x;
  float s = 0.0f;
  #pragma unroll
  for (int bj = 0; bj < NBJ; ++bj) s += partial[(size_t)bj * NROWS + r];
  float c = __logf(s) * (1.0f / (float)NROWS);
  #pragma unroll
  for (int off = 32; off >= 1; off >>= 1) c += __shfl_xor(c, off);
  __shared__ float wsum[4];
  if ((threadIdx.x & 63) == 0) wsum[threadIdx.x >> 6] = c;
  __syncthreads();
  if (threadIdx.x == 0) atomicAdd(out, wsum[0] + wsum[1] + wsum[2] + wsum[3]);
}

// -------- Kernel C2: positive-pair term; += -2*pos_i/2N for i<N ------------
__global__ void __launch_bounds__(1024) pos_kernel(
    const unsigned short* __restrict__ zn, float* __restrict__ out)
{
  const int w = threadIdx.x >> 6;
  const int lane = threadIdx.x & 63;
  const int row = blockIdx.x * 16 + w;   // [0, NHALF)
  const ushort4* p = (const ushort4*)(zn + (size_t)row * DDIM);
  const ushort4* q = (const ushort4*)(zn + (size_t)(row + NHALF) * DDIM);
  float dot = 0.0f;
  #pragma unroll
  for (int i = 0; i < 2; ++i) {
    ushort4 a = p[lane + i * 64], b = q[lane + i * 64];
    dot += bf2f(a.x)*bf2f(b.x) + bf2f(a.y)*bf2f(b.y)
         + bf2f(a.z)*bf2f(b.z) + bf2f(a.w)*bf2f(b.w);
  }
  #pragma unroll
  for (int off = 32; off >= 1; off >>= 1) dot += __shfl_xor(dot, off);
  __shared__ float wsum[16];
  if (lane == 0) wsum[w] = -2.0f * dot * INV_TAU * (1.0f / (float)NROWS);
  __syncthreads();
  if (threadIdx.x == 0) {
    float tt = 0.0f;
    #pragma unroll
    for (int i = 0; i < 16; ++i) tt += wsum[i];
    atomicAdd(out, tt);
  }
}

extern "C" void kernel_launch(void* const* d_in, const int* in_sizes, int n_in,
                              void* d_out, int out_size, void* d_ws, size_t ws_size,
                              hipStream_t stream)
{
  const float* x1 = (const float*)d_in[0];
  const float* x2 = (const float*)d_in[1];
  float* out = (float*)d_out;
  // ws layout: [0, 8MB) bf16 zn[8192][512]; [8MB, 10MB) f32 partial[64][8192]
  unsigned short* zn = (unsigned short*)d_ws;
  float* partial = (float*)((char*)d_ws + (size_t)NROWS * DDIM * sizeof(unsigned short));

  norm_kernel<<<NROWS / 4, 256, 0, stream>>>(x1, x2, zn, out);
  dim3 grid(NROWS / BM, NROWS / BN);
  simexp_kernel<<<grid, 256, 0, stream>>>(zn, partial);
  logdenom_kernel<<<NROWS / 256, 256, 0, stream>>>(partial, out);
  pos_kernel<<<NHALF / 16, 1024, 0, stream>>>(zn, out);
}

// Round 2
// 157.570 us; speedup vs baseline: 1.3450x; 1.3450x over previous
//
#include <hip/hip_runtime.h>
#include <cstdint>

#define NROWS 8192   // 2N
#define NHALF 4096   // N
#define DDIM  512
#define INV_TAU 10.0f
#define BM 128
#define BN 128
#define BK 64
#define NKT (DDIM / BK)   // 8
#define NP  (NROWS / BN)  // 64 column panels
#define NTRI (NP * (NP + 1) / 2)  // 2080 upper-triangle blocks

typedef __bf16 bf16x8 __attribute__((ext_vector_type(8)));
typedef float  f32x4  __attribute__((ext_vector_type(4)));

__device__ __forceinline__ unsigned short f2bf(float f) {
  unsigned int u = __float_as_uint(f);
  u += 0x7fffu + ((u >> 16) & 1u);   // round-to-nearest-even
  return (unsigned short)(u >> 16);
}
__device__ __forceinline__ float bf2f(unsigned short h) {
  return __uint_as_float(((unsigned int)h) << 16);
}

__device__ __forceinline__ void gload16(const void* g, void* l) {
  __builtin_amdgcn_global_load_lds(
      (__attribute__((address_space(1))) void*)g,
      (__attribute__((address_space(3))) void*)l, 16, 0, 0);
}

// ---------------- Kernel A: row-normalize to bf16, zero out ----------------
__global__ void __launch_bounds__(256) norm_kernel(
    const float* __restrict__ x1, const float* __restrict__ x2,
    unsigned short* __restrict__ zn, float* __restrict__ out)
{
  const int w = threadIdx.x >> 6;
  const int lane = threadIdx.x & 63;
  const int row = blockIdx.x * 4 + w;
  const float* src = (row < NHALF) ? (x1 + (size_t)row * DDIM)
                                   : (x2 + (size_t)(row - NHALF) * DDIM);
  const float4* s4 = (const float4*)src;
  float4 v0 = s4[lane];
  float4 v1 = s4[lane + 64];
  float ss = v0.x*v0.x + v0.y*v0.y + v0.z*v0.z + v0.w*v0.w
           + v1.x*v1.x + v1.y*v1.y + v1.z*v1.z + v1.w*v1.w;
  #pragma unroll
  for (int off = 32; off >= 1; off >>= 1) ss += __shfl_xor(ss, off);
  const float inv = 1.0f / fmaxf(sqrtf(ss), 1e-8f);
  ushort4 o0, o1;
  o0.x = f2bf(v0.x * inv); o0.y = f2bf(v0.y * inv);
  o0.z = f2bf(v0.z * inv); o0.w = f2bf(v0.w * inv);
  o1.x = f2bf(v1.x * inv); o1.y = f2bf(v1.y * inv);
  o1.z = f2bf(v1.z * inv); o1.w = f2bf(v1.w * inv);
  ushort4* d4 = (ushort4*)(zn + (size_t)row * DDIM);
  d4[lane] = o0;
  d4[lane + 64] = o1;
  if (row == 0 && lane == 0) out[0] = 0.0f;
}

// ------ Kernel B: fused Gram GEMM + exp + mask + row/col-sum ---------------
// Upper-triangle tiles only (sim is symmetric). Off-diagonal tiles scatter
// exp-sums into BOTH the row panel (rowsum) and the col panel (colsum).
// LDS chunk index XOR-swizzled by (row&7): kills the 128B-stride bank
// conflicts while keeping global_load_lds's lane-contiguous LDS dest.
__global__ void __launch_bounds__(256) simexp_kernel(
    const unsigned short* __restrict__ zn, float* __restrict__ partial)
{
  __shared__ unsigned short As[BM * BK];
  __shared__ unsigned short Bs[BN * BK];
  __shared__ float rowsum[2][BM];
  __shared__ float colsum[2][BN];

  // decode upper-triangle block index -> (bi, bj), bi <= bj
  const int idx = blockIdx.x;
  int bi = (int)((129.0f - sqrtf(129.0f * 129.0f - 8.0f * (float)idx)) * 0.5f);
  while (bi * NP - bi * (bi - 1) / 2 > idx) --bi;
  while ((bi + 1) * NP - (bi + 1) * bi / 2 <= idx) ++bi;
  const int bj = bi + (idx - (bi * NP - bi * (bi - 1) / 2));

  const int t = threadIdx.x;
  const int lane = t & 63;
  const int w = t >> 6;
  const int waveRow = w & 1;   // 2x2 waves -> 64x64 quadrant each
  const int waveCol = w >> 1;
  const int rowBase = bi * BM;
  const int colBase = bj * BN;
  const int quad = lane >> 4;
  const int cl = lane & 15;

  f32x4 acc[4][4];
  #pragma unroll
  for (int i = 0; i < 4; ++i)
    #pragma unroll
    for (int j = 0; j < 4; ++j)
      acc[i][j] = (f32x4)0.0f;

  for (int kt = 0; kt < NKT; ++kt) {
    const int kbase = kt * BK;
    // stage A (128xBK) and B (128xBK): 1024 16B chunks, 4/thread.
    // LDS slot (rr, k8) holds global chunk (rr, k8 ^ (rr&7)).
    #pragma unroll
    for (int qq = 0; qq < 4; ++qq) {
      const int chunk = qq * 256 + t;
      const int rr = chunk >> 3;               // tile row
      const int k8 = (chunk & 7) ^ (rr & 7);   // swizzled global 16B chunk
      gload16(zn + (size_t)(rowBase + rr) * DDIM + kbase + k8 * 8, &As[chunk * 8]);
      gload16(zn + (size_t)(colBase + rr) * DDIM + kbase + k8 * 8, &Bs[chunk * 8]);
    }
    __syncthreads();
    #pragma unroll
    for (int ks = 0; ks < 2; ++ks) {
      bf16x8 a[4], b[4];
      #pragma unroll
      for (int ti = 0; ti < 4; ++ti) {
        const int R = waveRow * 64 + ti * 16 + cl;
        const int c = ks * 4 + quad;           // 16B chunk within row
        a[ti] = *(const bf16x8*)&As[R * BK + ((c ^ (R & 7)) << 3)];
      }
      #pragma unroll
      for (int tj = 0; tj < 4; ++tj) {
        const int R = waveCol * 64 + tj * 16 + cl;
        const int c = ks * 4 + quad;
        b[tj] = *(const bf16x8*)&Bs[R * BK + ((c ^ (R & 7)) << 3)];
      }
      #pragma unroll
      for (int ti = 0; ti < 4; ++ti)
        #pragma unroll
        for (int tj = 0; tj < 4; ++tj)
          acc[ti][tj] = __builtin_amdgcn_mfma_f32_16x16x32_bf16(
              a[ti], b[tj], acc[ti][tj], 0, 0, 0);
    }
    __syncthreads();
  }

  // epilogue: e = exp(10*sim) with mask (r%N == c%N); row sums + col sums
  float colacc[4] = {0.0f, 0.0f, 0.0f, 0.0f};
  #pragma unroll
  for (int ti = 0; ti < 4; ++ti) {
    #pragma unroll
    for (int r = 0; r < 4; ++r) {
      const int lrow = waveRow * 64 + ti * 16 + quad * 4 + r;  // C/D: row=(lane>>4)*4+reg
      const int grow = rowBase + lrow;
      float s = 0.0f;
      #pragma unroll
      for (int tj = 0; tj < 4; ++tj) {
        const int gcol = colBase + waveCol * 64 + tj * 16 + cl; // C/D: col=lane&15
        const float e = (((grow ^ gcol) & (NHALF - 1)) == 0)
                        ? 0.0f : __expf(acc[ti][tj][r] * INV_TAU);
        s += e;
        colacc[tj] += e;
      }
      s += __shfl_xor(s, 1); s += __shfl_xor(s, 2);
      s += __shfl_xor(s, 4); s += __shfl_xor(s, 8);
      if (cl == 0) rowsum[waveCol][lrow] = s;
    }
  }
  if (bi != bj) {
    #pragma unroll
    for (int tj = 0; tj < 4; ++tj) {
      float c = colacc[tj];
      c += __shfl_xor(c, 16); c += __shfl_xor(c, 32);
      if (quad == 0) colsum[waveRow][waveCol * 64 + tj * 16 + cl] = c;
    }
  }
  __syncthreads();
  if (t < BM)
    partial[(size_t)bj * NROWS + rowBase + t] = rowsum[0][t] + rowsum[1][t];
  if (bi != bj && t < BN)
    partial[(size_t)bi * NROWS + colBase + t] = colsum[0][t] + colsum[1][t];
}

// -------- Kernel C1: denom = sum over col-panels; += log(denom)/2N ---------
__global__ void __launch_bounds__(256) logdenom_kernel(
    const float* __restrict__ partial, float* __restrict__ out)
{
  const int r = blockIdx.x * 256 + threadIdx.x;
  float s = 0.0f;
  #pragma unroll
  for (int bj = 0; bj < NP; ++bj) s += partial[(size_t)bj * NROWS + r];
  float c = __logf(s) * (1.0f / (float)NROWS);
  #pragma unroll
  for (int off = 32; off >= 1; off >>= 1) c += __shfl_xor(c, off);
  __shared__ float wsum[4];
  if ((threadIdx.x & 63) == 0) wsum[threadIdx.x >> 6] = c;
  __syncthreads();
  if (threadIdx.x == 0) atomicAdd(out, wsum[0] + wsum[1] + wsum[2] + wsum[3]);
}

// -------- Kernel C2: positive-pair term; += -2*pos_i/2N for i<N ------------
__global__ void __launch_bounds__(1024) pos_kernel(
    const unsigned short* __restrict__ zn, float* __restrict__ out)
{
  const int w = threadIdx.x >> 6;
  const int lane = threadIdx.x & 63;
  const int row = blockIdx.x * 16 + w;   // [0, NHALF)
  const ushort4* p = (const ushort4*)(zn + (size_t)row * DDIM);
  const ushort4* q = (const ushort4*)(zn + (size_t)(row + NHALF) * DDIM);
  float dot = 0.0f;
  #pragma unroll
  for (int i = 0; i < 2; ++i) {
    ushort4 a = p[lane + i * 64], b = q[lane + i * 64];
    dot += bf2f(a.x)*bf2f(b.x) + bf2f(a.y)*bf2f(b.y)
         + bf2f(a.z)*bf2f(b.z) + bf2f(a.w)*bf2f(b.w);
  }
  #pragma unroll
  for (int off = 32; off >= 1; off >>= 1) dot += __shfl_xor(dot, off);
  __shared__ float wsum[16];
  if (lane == 0) wsum[w] = -2.0f * dot * INV_TAU * (1.0f / (float)NROWS);
  __syncthreads();
  if (threadIdx.x == 0) {
    float tt = 0.0f;
    #pragma unroll
    for (int i = 0; i < 16; ++i) tt += wsum[i];
    atomicAdd(out, tt);
  }
}

extern "C" void kernel_launch(void* const* d_in, const int* in_sizes, int n_in,
                              void* d_out, int out_size, void* d_ws, size_t ws_size,
                              hipStream_t stream)
{
  const float* x1 = (const float*)d_in[0];
  const float* x2 = (const float*)d_in[1];
  float* out = (float*)d_out;
  // ws layout: [0, 8MB) bf16 zn[8192][512]; [8MB, 10MB) f32 partial[64][8192]
  unsigned short* zn = (unsigned short*)d_ws;
  float* partial = (float*)((char*)d_ws + (size_t)NROWS * DDIM * sizeof(unsigned short));

  norm_kernel<<<NROWS / 4, 256, 0, stream>>>(x1, x2, zn, out);
  simexp_kernel<<<NTRI, 256, 0, stream>>>(zn, partial);
  logdenom_kernel<<<NROWS / 256, 256, 0, stream>>>(partial, out);
  pos_kernel<<<NHALF / 16, 1024, 0, stream>>>(zn, out);
}

// Round 3
// 122.195 us; speedup vs baseline: 1.7344x; 1.2895x over previous
//
#include <hip/hip_runtime.h>
#include <cstdint>

#define NROWS 8192   // 2N
#define NHALF 4096   // N
#define DDIM  512
#define INV_TAU 10.0f
#define BM 128
#define BN 128
#define BKB 128              // bytes (=fp8 elems) of K per stage iteration
#define NKT (DDIM / BKB)     // 4
#define NP  (NROWS / BN)     // 64 column panels
#define NTRI (NP * (NP + 1) / 2)  // 2080 upper-triangle blocks

typedef float f32x4 __attribute__((ext_vector_type(4)));

__device__ __forceinline__ void gload16(const void* g, void* l) {
  __builtin_amdgcn_global_load_lds(
      (__attribute__((address_space(1))) void*)g,
      (__attribute__((address_space(3))) void*)l, 16, 0, 0);
}

// ---- Kernel A: row-normalize -> fp8 e4m3, fused positive-pair dot (fp32) ----
// Block = 4 waves: waves 0,1 handle rows pr,pr+1 (first half); waves 2,3 the
// paired rows pr+N,pr+1+N. Pos dot computed exactly in fp32 via LDS exchange.
__global__ void __launch_bounds__(256) norm_kernel(
    const float* __restrict__ x1, const float* __restrict__ x2,
    unsigned char* __restrict__ z8, float* __restrict__ posv,
    float* __restrict__ out)
{
  __shared__ float zsh[2][DDIM];
  const int w = threadIdx.x >> 6;
  const int lane = threadIdx.x & 63;
  const int pr = blockIdx.x * 2 + (w & 1);   // pair index in [0, NHALF)
  const bool second = (w >= 2);
  const int row = second ? pr + NHALF : pr;
  const float* src = second ? (x2 + (size_t)pr * DDIM) : (x1 + (size_t)pr * DDIM);

  const float4* s4 = (const float4*)src;
  float4 v0 = s4[lane];
  float4 v1 = s4[lane + 64];
  float ss = v0.x*v0.x + v0.y*v0.y + v0.z*v0.z + v0.w*v0.w
           + v1.x*v1.x + v1.y*v1.y + v1.z*v1.z + v1.w*v1.w;
  #pragma unroll
  for (int off = 32; off >= 1; off >>= 1) ss += __shfl_xor(ss, off);
  const float inv = 1.0f / fmaxf(sqrtf(ss), 1e-8f);
  v0.x *= inv; v0.y *= inv; v0.z *= inv; v0.w *= inv;
  v1.x *= inv; v1.y *= inv; v1.z *= inv; v1.w *= inv;

  // pack 8 fp8 (OCP e4m3, RNE+sat via v_cvt_pk_fp8_f32) and store 2x4B
  int p01 = __builtin_amdgcn_cvt_pk_fp8_f32(v0.x, v0.y, 0, false);
  int p23 = __builtin_amdgcn_cvt_pk_fp8_f32(v0.z, v0.w, 0, false);
  int p45 = __builtin_amdgcn_cvt_pk_fp8_f32(v1.x, v1.y, 0, false);
  int p67 = __builtin_amdgcn_cvt_pk_fp8_f32(v1.z, v1.w, 0, false);
  unsigned int* d = (unsigned int*)(z8 + (size_t)row * DDIM);
  d[lane]      = (p01 & 0xffff) | (p23 << 16);
  d[lane + 64] = (p45 & 0xffff) | (p67 << 16);

  // positive-pair dot in exact fp32
  if (second) {
    float4* sh = (float4*)zsh[w - 2];
    sh[lane]      = v0;
    sh[lane + 64] = v1;
  }
  __syncthreads();
  if (!second) {
    const float4* sh = (const float4*)zsh[w];
    float4 p0 = sh[lane], p1 = sh[lane + 64];
    float dot = v0.x*p0.x + v0.y*p0.y + v0.z*p0.z + v0.w*p0.w
              + v1.x*p1.x + v1.y*p1.y + v1.z*p1.z + v1.w*p1.w;
    #pragma unroll
    for (int off = 32; off >= 1; off >>= 1) dot += __shfl_xor(dot, off);
    if (lane == 0) posv[pr] = dot;
  }
  if (blockIdx.x == 0 && threadIdx.x == 0) out[0] = 0.0f;
}

// ------ Kernel B: fp8 Gram GEMM + exp + mask + row/col-sum (upper tri) ------
// BK=128 fp8 elements per stage (4 iters). 16B-chunk XOR swizzle keeps
// bank conflicts at 0 while preserving global_load_lds lane-contiguity.
__global__ void __launch_bounds__(256) simexp_kernel(
    const unsigned char* __restrict__ z8, float* __restrict__ partial)
{
  __shared__ unsigned char As[BM * BKB];   // 16 KB
  __shared__ unsigned char Bs[BN * BKB];   // 16 KB
  __shared__ float rowsum[2][BM];
  __shared__ float colsum[2][BN];

  // decode upper-triangle block index -> (bi, bj), bi <= bj
  const int idx = blockIdx.x;
  int bi = (int)((129.0f - sqrtf(129.0f * 129.0f - 8.0f * (float)idx)) * 0.5f);
  while (bi * NP - bi * (bi - 1) / 2 > idx) --bi;
  while ((bi + 1) * NP - (bi + 1) * bi / 2 <= idx) ++bi;
  const int bj = bi + (idx - (bi * NP - bi * (bi - 1) / 2));

  const int t = threadIdx.x;
  const int lane = t & 63;
  const int w = t >> 6;
  const int waveRow = w & 1;   // 2x2 waves -> 64x64 quadrant each
  const int waveCol = w >> 1;
  const int rowBase = bi * BM;
  const int colBase = bj * BN;
  const int quad = lane >> 4;
  const int cl = lane & 15;

  f32x4 acc[4][4];
  #pragma unroll
  for (int i = 0; i < 4; ++i)
    #pragma unroll
    for (int j = 0; j < 4; ++j)
      acc[i][j] = (f32x4)0.0f;

  for (int kt = 0; kt < NKT; ++kt) {
    const int kbase = kt * BKB;
    // stage A,B (128 x 128B each): 1024 16B chunks per panel, 8 gload/thread
    #pragma unroll
    for (int qq = 0; qq < 4; ++qq) {
      const int chunk = qq * 256 + t;          // 0..1023
      const int rr = chunk >> 3;               // tile row
      const int k8 = (chunk & 7) ^ (rr & 7);   // swizzled 16B chunk in row
      gload16(z8 + (size_t)(rowBase + rr) * DDIM + kbase + k8 * 16, &As[chunk * 16]);
      gload16(z8 + (size_t)(colBase + rr) * DDIM + kbase + k8 * 16, &Bs[chunk * 16]);
    }
    __syncthreads();
    #pragma unroll
    for (int ks = 0; ks < 4; ++ks) {           // 32 fp8 elems per MFMA k-step
      const int o = ks * 32 + quad * 8;        // byte offset within row
      const int c16 = o >> 4, o8 = o & 8;
      long a[4], b[4];
      #pragma unroll
      for (int ti = 0; ti < 4; ++ti) {
        const int R = waveRow * 64 + ti * 16 + cl;
        a[ti] = *(const long*)&As[R * BKB + ((c16 ^ (R & 7)) << 4) + o8];
      }
      #pragma unroll
      for (int tj = 0; tj < 4; ++tj) {
        const int R = waveCol * 64 + tj * 16 + cl;
        b[tj] = *(const long*)&Bs[R * BKB + ((c16 ^ (R & 7)) << 4) + o8];
      }
      #pragma unroll
      for (int ti = 0; ti < 4; ++ti)
        #pragma unroll
        for (int tj = 0; tj < 4; ++tj)
          acc[ti][tj] = __builtin_amdgcn_mfma_f32_16x16x32_fp8_fp8(
              a[ti], b[tj], acc[ti][tj], 0, 0, 0);
    }
    __syncthreads();
  }

  // epilogue: e = exp(10*sim) with mask (r%N == c%N); row sums + col sums
  float colacc[4] = {0.0f, 0.0f, 0.0f, 0.0f};
  #pragma unroll
  for (int ti = 0; ti < 4; ++ti) {
    #pragma unroll
    for (int r = 0; r < 4; ++r) {
      const int lrow = waveRow * 64 + ti * 16 + quad * 4 + r;  // C/D: row=(lane>>4)*4+reg
      const int grow = rowBase + lrow;
      float s = 0.0f;
      #pragma unroll
      for (int tj = 0; tj < 4; ++tj) {
        const int gcol = colBase + waveCol * 64 + tj * 16 + cl; // C/D: col=lane&15
        const float e = (((grow ^ gcol) & (NHALF - 1)) == 0)
                        ? 0.0f : __expf(acc[ti][tj][r] * INV_TAU);
        s += e;
        colacc[tj] += e;
      }
      s += __shfl_xor(s, 1); s += __shfl_xor(s, 2);
      s += __shfl_xor(s, 4); s += __shfl_xor(s, 8);
      if (cl == 0) rowsum[waveCol][lrow] = s;
    }
  }
  if (bi != bj) {
    #pragma unroll
    for (int tj = 0; tj < 4; ++tj) {
      float c = colacc[tj];
      c += __shfl_xor(c, 16); c += __shfl_xor(c, 32);
      if (quad == 0) colsum[waveRow][waveCol * 64 + tj * 16 + cl] = c;
    }
  }
  __syncthreads();
  if (t < BM)
    partial[(size_t)bj * NROWS + rowBase + t] = rowsum[0][t] + rowsum[1][t];
  if (bi != bj && t < BN)
    partial[(size_t)bi * NROWS + colBase + t] = colsum[0][t] + colsum[1][t];
}

// -- Kernel C: denom reduce + log + positive term -> atomicAdd into out -----
__global__ void __launch_bounds__(256) logdenom_kernel(
    const float* __restrict__ partial, const float* __restrict__ posv,
    float* __restrict__ out)
{
  const int r = blockIdx.x * 256 + threadIdx.x;
  float s = 0.0f;
  #pragma unroll
  for (int bj = 0; bj < NP; ++bj) s += partial[(size_t)bj * NROWS + r];
  float c = __logf(s) * (1.0f / (float)NROWS);
  if (r < NHALF)   // each pos dot appears twice in the 2N-row mean
    c -= 2.0f * INV_TAU * posv[r] * (1.0f / (float)NROWS);
  #pragma unroll
  for (int off = 32; off >= 1; off >>= 1) c += __shfl_xor(c, off);
  __shared__ float wsum[4];
  if ((threadIdx.x & 63) == 0) wsum[threadIdx.x >> 6] = c;
  __syncthreads();
  if (threadIdx.x == 0) atomicAdd(out, wsum[0] + wsum[1] + wsum[2] + wsum[3]);
}

extern "C" void kernel_launch(void* const* d_in, const int* in_sizes, int n_in,
                              void* d_out, int out_size, void* d_ws, size_t ws_size,
                              hipStream_t stream)
{
  const float* x1 = (const float*)d_in[0];
  const float* x2 = (const float*)d_in[1];
  float* out = (float*)d_out;
  // ws layout: [0,4MB) fp8 z8[8192][512]; [4MB,6MB) f32 partial[64][8192];
  //            [6MB, +16KB) f32 posv[4096]
  unsigned char* z8 = (unsigned char*)d_ws;
  float* partial = (float*)((char*)d_ws + (size_t)NROWS * DDIM);
  float* posv = (float*)((char*)d_ws + (size_t)NROWS * DDIM + (size_t)NP * NROWS * 4);

  norm_kernel<<<NHALF / 2, 256, 0, stream>>>(x1, x2, z8, posv, out);
  simexp_kernel<<<NTRI, 256, 0, stream>>>(z8, partial);
  logdenom_kernel<<<NROWS / 256, 256, 0, stream>>>(partial, posv, out);
}